// Round 1
// baseline (728.859 us; speedup 1.0000x reference)
//
#include <hip/hip_runtime.h>
#include <math.h>

// Round 1: correctness-first full-fp32 pipeline.
//   wc_softmax -> ws.WCS
//   gemm_xwt   (query@Wq.T+bq -> Q, key->K, value->V)
//   flash_attn (S = QK^T/8 * (1+WCS), online softmax, PV) -> ws.A
//   gemm_xwt   (A@Wo.T+bo -> d_out)
// ws usage: 4x (8192x512 f32) + 8x1024x1024 f32 = 100.7 MB.

#define BS 8
#define SEQ 1024
#define DM 512
#define NH 8
#define DK 64
#define ROWS (BS * SEQ)  // 8192

// ---------------------------------------------------------------------------
// Row softmax of wc_matrix: 8192 rows of 1024.  One block (256 thr) per row.
// ---------------------------------------------------------------------------
__global__ __launch_bounds__(256) void wc_softmax_kernel(const float* __restrict__ wc,
                                                         float* __restrict__ out) {
  int row = blockIdx.x;
  const float* x = wc + (size_t)row * SEQ;
  float* y = out + (size_t)row * SEQ;
  int t = threadIdx.x;
  float4 v = *(const float4*)(x + t * 4);
  float m = fmaxf(fmaxf(v.x, v.y), fmaxf(v.z, v.w));
#pragma unroll
  for (int off = 32; off > 0; off >>= 1) m = fmaxf(m, __shfl_xor(m, off, 64));
  __shared__ float sm[4], ss[4];
  int w = t >> 6;
  if ((t & 63) == 0) sm[w] = m;
  __syncthreads();
  m = fmaxf(fmaxf(sm[0], sm[1]), fmaxf(sm[2], sm[3]));
  float4 e;
  e.x = __expf(v.x - m);
  e.y = __expf(v.y - m);
  e.z = __expf(v.z - m);
  e.w = __expf(v.w - m);
  float s = e.x + e.y + e.z + e.w;
#pragma unroll
  for (int off = 32; off > 0; off >>= 1) s += __shfl_xor(s, off, 64);
  if ((t & 63) == 0) ss[w] = s;
  __syncthreads();
  s = ss[0] + ss[1] + ss[2] + ss[3];
  float inv = 1.0f / s;
  e.x *= inv;
  e.y *= inv;
  e.z *= inv;
  e.w *= inv;
  *(float4*)(y + t * 4) = e;
}

// ---------------------------------------------------------------------------
// C[M=8192, 512] = X[8192,512] @ W[512,512]^T + bias.   fp32 tiled GEMM.
// 128x128 block tile, BK=16, 256 threads, 8x8 per-thread register tile.
// ---------------------------------------------------------------------------
__global__ __launch_bounds__(256) void gemm_xwt_kernel(const float* __restrict__ X,
                                                       const float* __restrict__ W,
                                                       const float* __restrict__ bias,
                                                       float* __restrict__ C) {
  __shared__ float Xs[16][128];  // [k][m]
  __shared__ float Ws[16][128];  // [k][n]
  int t = threadIdx.x;
  int tx = t & 15, ty = t >> 4;
  int mbase = blockIdx.x * 128;
  int nbase = blockIdx.y * 128;
  int lrow = t >> 2;        // 0..63
  int lk = (t & 3) * 4;     // 0,4,8,12
  float acc[8][8];
#pragma unroll
  for (int i = 0; i < 8; ++i)
#pragma unroll
    for (int j = 0; j < 8; ++j) acc[i][j] = 0.f;

  for (int kb = 0; kb < DM; kb += 16) {
    float4 xa = *(const float4*)(X + (size_t)(mbase + lrow) * DM + kb + lk);
    float4 xb = *(const float4*)(X + (size_t)(mbase + lrow + 64) * DM + kb + lk);
    float4 wa = *(const float4*)(W + (size_t)(nbase + lrow) * DM + kb + lk);
    float4 wb = *(const float4*)(W + (size_t)(nbase + lrow + 64) * DM + kb + lk);
    __syncthreads();  // previous iteration's readers are done
    Xs[lk + 0][lrow] = xa.x; Xs[lk + 1][lrow] = xa.y; Xs[lk + 2][lrow] = xa.z; Xs[lk + 3][lrow] = xa.w;
    Xs[lk + 0][lrow + 64] = xb.x; Xs[lk + 1][lrow + 64] = xb.y; Xs[lk + 2][lrow + 64] = xb.z; Xs[lk + 3][lrow + 64] = xb.w;
    Ws[lk + 0][lrow] = wa.x; Ws[lk + 1][lrow] = wa.y; Ws[lk + 2][lrow] = wa.z; Ws[lk + 3][lrow] = wa.w;
    Ws[lk + 0][lrow + 64] = wb.x; Ws[lk + 1][lrow + 64] = wb.y; Ws[lk + 2][lrow + 64] = wb.z; Ws[lk + 3][lrow + 64] = wb.w;
    __syncthreads();
#pragma unroll
    for (int kk = 0; kk < 16; ++kk) {
      float a[8], b[8];
      *(float4*)(a) = *(const float4*)(&Xs[kk][ty * 8]);
      *(float4*)(a + 4) = *(const float4*)(&Xs[kk][ty * 8 + 4]);
      *(float4*)(b) = *(const float4*)(&Ws[kk][tx * 8]);
      *(float4*)(b + 4) = *(const float4*)(&Ws[kk][tx * 8 + 4]);
#pragma unroll
      for (int i = 0; i < 8; ++i)
#pragma unroll
        for (int j = 0; j < 8; ++j) acc[i][j] = fmaf(a[i], b[j], acc[i][j]);
    }
  }

  int col = nbase + tx * 8;
  float4 b0 = *(const float4*)(bias + col);
  float4 b1 = *(const float4*)(bias + col + 4);
#pragma unroll
  for (int i = 0; i < 8; ++i) {
    int row = mbase + ty * 8 + i;
    float4 o0, o1;
    o0.x = acc[i][0] + b0.x; o0.y = acc[i][1] + b0.y; o0.z = acc[i][2] + b0.z; o0.w = acc[i][3] + b0.w;
    o1.x = acc[i][4] + b1.x; o1.y = acc[i][5] + b1.y; o1.z = acc[i][6] + b1.z; o1.w = acc[i][7] + b1.w;
    *(float4*)(C + (size_t)row * DM + col) = o0;
    *(float4*)(C + (size_t)row * DM + col + 4) = o1;
  }
}

// ---------------------------------------------------------------------------
// Flash attention per (b, h, 64-row q-tile).  fp32 VALU.
// S = (Q K^T / 8) * (1 + wc_sm);  online softmax;  O += P V.
// LDS: Qs[d][row], KPs (K tile [d][col], later aliased as P tile [m][row]),
//      Vs[m][d].  54 KB total -> <=64 KB/workgroup limit, ~2-3 blocks/CU.
// ---------------------------------------------------------------------------
__global__ __launch_bounds__(256) void flash_attn_kernel(const float* __restrict__ Q,
                                                         const float* __restrict__ K,
                                                         const float* __restrict__ V,
                                                         const float* __restrict__ WCS,
                                                         float* __restrict__ A) {
  int qt = blockIdx.x;  // 0..15
  int h = blockIdx.y;   // 0..7
  int b = blockIdx.z;   // 0..7
  __shared__ float Qs[64][64];   // [d][row]
  __shared__ float KPs[64][64];  // K: [d][col]; later P: [m][row]
  __shared__ float Vs[64][64];   // [m][d]
  __shared__ float red[64][16];
  __shared__ float mrow[64], lrow[64], arow[64];
  int t = threadIdx.x;
  int tx = t & 15, ty = t >> 4;
  int r0 = ty * 4;  // S/O row base (query rows)
  int c0 = tx * 4;  // S col base / O d base
  size_t qrow0 = (size_t)(b * SEQ + qt * 64);

  // load Q tile -> Qs[d][row]
#pragma unroll
  for (int f = 0; f < 4; ++f) {
    int fid = t + f * 256;  // 0..1023
    int row = fid >> 4;
    int d4 = (fid & 15) * 4;
    float4 v = *(const float4*)(Q + (qrow0 + row) * DM + h * DK + d4);
    Qs[d4 + 0][row] = v.x; Qs[d4 + 1][row] = v.y; Qs[d4 + 2][row] = v.z; Qs[d4 + 3][row] = v.w;
  }
  if (t < 64) {
    mrow[t] = -INFINITY;
    lrow[t] = 0.f;
  }
  float o[4][4];
#pragma unroll
  for (int i = 0; i < 4; ++i)
#pragma unroll
    for (int j = 0; j < 4; ++j) o[i][j] = 0.f;

  for (int mt = 0; mt < 16; ++mt) {
    __syncthreads();  // previous tile's PV readers done; Q load visible (mt==0)
    size_t krow0 = (size_t)(b * SEQ + mt * 64);
#pragma unroll
    for (int f = 0; f < 4; ++f) {
      int fid = t + f * 256;
      int row = fid >> 4;
      int d4 = (fid & 15) * 4;
      float4 kv = *(const float4*)(K + (krow0 + row) * DM + h * DK + d4);
      KPs[d4 + 0][row] = kv.x; KPs[d4 + 1][row] = kv.y; KPs[d4 + 2][row] = kv.z; KPs[d4 + 3][row] = kv.w;
      float4 vv = *(const float4*)(V + (krow0 + row) * DM + h * DK + d4);
      *(float4*)(&Vs[row][d4]) = vv;
    }
    __syncthreads();

    // S fragment: 4x4 per thread
    float s[4][4];
#pragma unroll
    for (int i = 0; i < 4; ++i)
#pragma unroll
      for (int j = 0; j < 4; ++j) s[i][j] = 0.f;
    for (int d = 0; d < 64; ++d) {
      float4 q4 = *(const float4*)(&Qs[d][r0]);
      float4 k4 = *(const float4*)(&KPs[d][c0]);
      float qa[4] = {q4.x, q4.y, q4.z, q4.w};
      float kb[4] = {k4.x, k4.y, k4.z, k4.w};
#pragma unroll
      for (int i = 0; i < 4; ++i)
#pragma unroll
        for (int j = 0; j < 4; ++j) s[i][j] = fmaf(qa[i], kb[j], s[i][j]);
    }
    // scale + WC modulation: s = (s/8) * (1 + wc_sm)
#pragma unroll
    for (int i = 0; i < 4; ++i) {
      float4 wc = *(const float4*)(WCS + (qrow0 + r0 + i) * SEQ + mt * 64 + c0);
      s[i][0] = s[i][0] * 0.125f * (1.f + wc.x);
      s[i][1] = s[i][1] * 0.125f * (1.f + wc.y);
      s[i][2] = s[i][2] * 0.125f * (1.f + wc.z);
      s[i][3] = s[i][3] * 0.125f * (1.f + wc.w);
    }
    // row-max partials
#pragma unroll
    for (int i = 0; i < 4; ++i)
      red[r0 + i][tx] = fmaxf(fmaxf(s[i][0], s[i][1]), fmaxf(s[i][2], s[i][3]));
    __syncthreads();
    if (t < 64) {
      float mt_ = red[t][0];
#pragma unroll
      for (int j = 1; j < 16; ++j) mt_ = fmaxf(mt_, red[t][j]);
      float mnew = fmaxf(mrow[t], mt_);
      arow[t] = __expf(mrow[t] - mnew);
      mrow[t] = mnew;
      lrow[t] *= arow[t];
    }
    __syncthreads();
    // P = exp(s - m); write into KPs as [m][row]; partial row sums
#pragma unroll
    for (int i = 0; i < 4; ++i) {
      float a_ = arow[r0 + i];
      float mn = mrow[r0 + i];
      float rs = 0.f;
#pragma unroll
      for (int j = 0; j < 4; ++j) {
        o[i][j] *= a_;
        float p = __expf(s[i][j] - mn);
        KPs[c0 + j][r0 + i] = p;
        rs += p;
      }
      red[r0 + i][tx] = rs;
    }
    __syncthreads();
    if (t < 64) {
      float rs = 0.f;
#pragma unroll
      for (int j = 0; j < 16; ++j) rs += red[t][j];
      lrow[t] += rs;
    }
    __syncthreads();
    // O += P V
    for (int m = 0; m < 64; ++m) {
      float4 p4 = *(const float4*)(&KPs[m][r0]);
      float4 v4 = *(const float4*)(&Vs[m][c0]);
      float pa[4] = {p4.x, p4.y, p4.z, p4.w};
      float vb[4] = {v4.x, v4.y, v4.z, v4.w};
#pragma unroll
      for (int i = 0; i < 4; ++i)
#pragma unroll
        for (int j = 0; j < 4; ++j) o[i][j] = fmaf(pa[i], vb[j], o[i][j]);
    }
  }

  // epilogue: divide by l, write A[b, n, h*64 + d]
#pragma unroll
  for (int i = 0; i < 4; ++i) {
    float inv = 1.0f / lrow[r0 + i];
    float4 o4;
    o4.x = o[i][0] * inv;
    o4.y = o[i][1] * inv;
    o4.z = o[i][2] * inv;
    o4.w = o[i][3] * inv;
    *(float4*)(A + (qrow0 + r0 + i) * DM + h * DK + c0) = o4;
  }
}

// ---------------------------------------------------------------------------
extern "C" void kernel_launch(void* const* d_in, const int* in_sizes, int n_in,
                              void* d_out, int out_size, void* d_ws, size_t ws_size,
                              hipStream_t stream) {
  const float* query = (const float*)d_in[0];
  const float* key = (const float*)d_in[1];
  const float* value = (const float*)d_in[2];
  const float* wc = (const float*)d_in[3];
  const float* Wq = (const float*)d_in[4];
  const float* bq = (const float*)d_in[5];
  const float* Wk = (const float*)d_in[6];
  const float* bk = (const float*)d_in[7];
  const float* Wv = (const float*)d_in[8];
  const float* bv = (const float*)d_in[9];
  const float* Wo = (const float*)d_in[10];
  const float* bo = (const float*)d_in[11];
  float* out = (float*)d_out;

  float* Qb = (float*)d_ws;
  float* Kb = Qb + (size_t)ROWS * DM;
  float* Vb = Kb + (size_t)ROWS * DM;
  float* Ab = Vb + (size_t)ROWS * DM;
  float* WCS = Ab + (size_t)ROWS * DM;  // 8*1024*1024 floats

  wc_softmax_kernel<<<BS * SEQ, 256, 0, stream>>>(wc, WCS);

  dim3 gg(ROWS / 128, DM / 128);
  gemm_xwt_kernel<<<gg, 256, 0, stream>>>(query, Wq, bq, Qb);
  gemm_xwt_kernel<<<gg, 256, 0, stream>>>(key, Wk, bk, Kb);
  gemm_xwt_kernel<<<gg, 256, 0, stream>>>(value, Wv, bv, Vb);

  dim3 ga(SEQ / 64, NH, BS);
  flash_attn_kernel<<<ga, 256, 0, stream>>>(Qb, Kb, Vb, WCS, Ab);

  gemm_xwt_kernel<<<gg, 256, 0, stream>>>(Ab, Wo, bo, out);
}

// Round 2
// 315.358 us; speedup vs baseline: 2.3112x; 2.3112x over previous
//
#include <hip/hip_runtime.h>
#include <math.h>

// Round 2: bf16 MFMA everywhere (16x16x32, fp32 accumulate).
//   wc_softmax  -> G = 1 + softmax(wc)            (bf16, 8x1024x1024)
//   gemm_mfma   -> Qb, Kb, Vb = X @ W.T + b       (fp32 in, bf16 out)
//   vtrans      -> Vt[bh][d][m]                   (bf16, per-head transpose)
//   flash_mfma  -> Ab (online softmax, S=QK^T/8*G) (bf16)
//   gemm_mfma   -> out = Ab @ Wo.T + bo           (bf16 in, fp32 out)

#define BS 8
#define SEQ 1024
#define DM 512
#define NH 8
#define DK 64
#define ROWS (BS * SEQ)

typedef __bf16 bf16_t;
typedef bf16_t bf16x8 __attribute__((ext_vector_type(8)));
typedef bf16_t bf16x4 __attribute__((ext_vector_type(4)));
typedef float f32x4 __attribute__((ext_vector_type(4)));

__device__ inline f32x4 mfma16(bf16x8 a, bf16x8 b, f32x4 c) {
  return __builtin_amdgcn_mfma_f32_16x16x32_bf16(a, b, c, 0, 0, 0);
}

__device__ inline bf16x8 cvt8(float4 a, float4 b) {
  bf16x8 r;
  r[0] = (bf16_t)a.x; r[1] = (bf16_t)a.y; r[2] = (bf16_t)a.z; r[3] = (bf16_t)a.w;
  r[4] = (bf16_t)b.x; r[5] = (bf16_t)b.y; r[6] = (bf16_t)b.z; r[7] = (bf16_t)b.w;
  return r;
}

// ---------------------------------------------------------------------------
// G = 1 + softmax(wc) per row, bf16 out.  One block (256 thr) per row.
// ---------------------------------------------------------------------------
__global__ __launch_bounds__(256) void wc_softmax_kernel(const float* __restrict__ wc,
                                                         bf16_t* __restrict__ G) {
  int row = blockIdx.x;
  const float* x = wc + (size_t)row * SEQ;
  bf16_t* y = G + (size_t)row * SEQ;
  int t = threadIdx.x;
  float4 v = *(const float4*)(x + t * 4);
  float m = fmaxf(fmaxf(v.x, v.y), fmaxf(v.z, v.w));
#pragma unroll
  for (int off = 32; off > 0; off >>= 1) m = fmaxf(m, __shfl_xor(m, off, 64));
  __shared__ float sm[4], ss[4];
  int w = t >> 6;
  if ((t & 63) == 0) sm[w] = m;
  __syncthreads();
  m = fmaxf(fmaxf(sm[0], sm[1]), fmaxf(sm[2], sm[3]));
  float4 e;
  e.x = __expf(v.x - m); e.y = __expf(v.y - m);
  e.z = __expf(v.z - m); e.w = __expf(v.w - m);
  float s = e.x + e.y + e.z + e.w;
#pragma unroll
  for (int off = 32; off > 0; off >>= 1) s += __shfl_xor(s, off, 64);
  if ((t & 63) == 0) ss[w] = s;
  __syncthreads();
  s = ss[0] + ss[1] + ss[2] + ss[3];
  float inv = 1.0f / s;
  bf16x4 g;
  g[0] = (bf16_t)(1.0f + e.x * inv);
  g[1] = (bf16_t)(1.0f + e.y * inv);
  g[2] = (bf16_t)(1.0f + e.z * inv);
  g[3] = (bf16_t)(1.0f + e.w * inv);
  *(bf16x4*)(y + t * 4) = g;
}

// ---------------------------------------------------------------------------
// C[8192,512] = X[8192,512] @ W[512,512]^T + bias.  MFMA bf16, fp32 acc.
// 128x128 tile, BK=32, 4 waves x (4x4 tiles of 16x16).
// XBF16: X already bf16 (else fp32, converted in staging). W always fp32.
// OUTF32: write fp32 (else bf16).
// ---------------------------------------------------------------------------
template <bool XBF16, bool OUTF32>
__global__ __launch_bounds__(256) void gemm_mfma(const void* __restrict__ Xv,
                                                 const float* __restrict__ W,
                                                 const float* __restrict__ bias,
                                                 void* __restrict__ Cv) {
  __shared__ bf16_t As[128][32];
  __shared__ bf16_t Bs[128][32];
  int t = threadIdx.x;
  int lane = t & 63, w = t >> 6;
  int quad = lane >> 4, l15 = lane & 15;
  int m0w = (w & 1) * 64, n0w = (w >> 1) * 64;
  int mbase = blockIdx.x * 128, nbase = blockIdx.y * 128;
  f32x4 acc[4][4] = {};

  for (int kb = 0; kb < DM; kb += 32) {
    __syncthreads();  // previous tile's readers done
    // stage A
    if (XBF16) {
      const bf16_t* X = (const bf16_t*)Xv;
#pragma unroll
      for (int f = 0; f < 2; ++f) {
        int chunk = t + f * 256;          // 0..511
        int row = chunk >> 2;             // 0..127
        int k8 = (chunk & 3) * 8;         // 0..24
        *(bf16x8*)&As[row][k8] =
            *(const bf16x8*)&X[(size_t)(mbase + row) * DM + kb + k8];
      }
    } else {
      const float* X = (const float*)Xv;
      int row = t >> 1, koff = (t & 1) * 16;
      const float* p = X + (size_t)(mbase + row) * DM + kb + koff;
      float4 x0 = *(const float4*)(p + 0);
      float4 x1 = *(const float4*)(p + 4);
      float4 x2 = *(const float4*)(p + 8);
      float4 x3 = *(const float4*)(p + 12);
      *(bf16x8*)&As[row][koff] = cvt8(x0, x1);
      *(bf16x8*)&As[row][koff + 8] = cvt8(x2, x3);
    }
    // stage B (W fp32)
    {
      int row = t >> 1, koff = (t & 1) * 16;
      const float* p = W + (size_t)(nbase + row) * DM + kb + koff;
      float4 x0 = *(const float4*)(p + 0);
      float4 x1 = *(const float4*)(p + 4);
      float4 x2 = *(const float4*)(p + 8);
      float4 x3 = *(const float4*)(p + 12);
      *(bf16x8*)&Bs[row][koff] = cvt8(x0, x1);
      *(bf16x8*)&Bs[row][koff + 8] = cvt8(x2, x3);
    }
    __syncthreads();
    bf16x8 af[4], bf[4];
#pragma unroll
    for (int mt = 0; mt < 4; ++mt)
      af[mt] = *(const bf16x8*)&As[m0w + mt * 16 + l15][quad * 8];
#pragma unroll
    for (int nt = 0; nt < 4; ++nt)
      bf[nt] = *(const bf16x8*)&Bs[n0w + nt * 16 + l15][quad * 8];
#pragma unroll
    for (int mt = 0; mt < 4; ++mt)
#pragma unroll
      for (int nt = 0; nt < 4; ++nt)
        acc[mt][nt] = mfma16(af[mt], bf[nt], acc[mt][nt]);
  }

#pragma unroll
  for (int nt = 0; nt < 4; ++nt) {
    int col = nbase + n0w + nt * 16 + l15;
    float bc = bias[col];
#pragma unroll
    for (int mt = 0; mt < 4; ++mt) {
#pragma unroll
      for (int r = 0; r < 4; ++r) {
        int row = mbase + m0w + mt * 16 + quad * 4 + r;
        float v = acc[mt][nt][r] + bc;
        if (OUTF32)
          ((float*)Cv)[(size_t)row * DM + col] = v;
        else
          ((bf16_t*)Cv)[(size_t)row * DM + col] = (bf16_t)v;
      }
    }
  }
}

// ---------------------------------------------------------------------------
// Vt[(b*8+h)*64 + d][m] = Vb[b*1024 + m][h*64 + d]   (bf16 -> bf16)
// ---------------------------------------------------------------------------
__global__ __launch_bounds__(256) void vtrans_kernel(const bf16_t* __restrict__ Vb,
                                                     bf16_t* __restrict__ Vt) {
  int mt = blockIdx.x;  // 0..15
  int bh = blockIdx.y;  // 0..63
  int b = bh >> 3, h = bh & 7;
  __shared__ bf16_t Ts[64][66];  // [d][m], padded
  int t = threadIdx.x;
#pragma unroll
  for (int f = 0; f < 2; ++f) {
    int chunk = t + f * 256;   // 0..511
    int row = chunk >> 3;      // m-local 0..63
    int c8 = (chunk & 7) * 8;  // d-local
    bf16x8 v = *(const bf16x8*)&Vb[(size_t)(b * SEQ + mt * 64 + row) * DM + h * DK + c8];
#pragma unroll
    for (int j = 0; j < 8; ++j) Ts[c8 + j][row] = v[j];
  }
  __syncthreads();
#pragma unroll
  for (int f = 0; f < 2; ++f) {
    int chunk = t + f * 256;
    int d = chunk >> 3;
    int m8 = (chunk & 7) * 8;
    bf16x8 o;
#pragma unroll
    for (int j = 0; j < 8; ++j) o[j] = Ts[d][m8 + j];
    *(bf16x8*)&Vt[((size_t)(bh * DK + d)) * SEQ + mt * 64 + m8] = o;
  }
}

// ---------------------------------------------------------------------------
// Flash attention, MFMA.  Block = (qtile 64 rows, h, b), 4 waves.
// Wave w owns q-rows w*16..w*16+15.  S = (Q K^T / 8) * G; online softmax in
// registers (row state replicated across each 16-lane quad); P via LDS to
// A-layout; O += P V.
// ---------------------------------------------------------------------------
__global__ __launch_bounds__(256) void flash_mfma_kernel(const bf16_t* __restrict__ Qb,
                                                         const bf16_t* __restrict__ Kb,
                                                         const bf16_t* __restrict__ Vt,
                                                         const bf16_t* __restrict__ G,
                                                         bf16_t* __restrict__ Ab) {
  int qt = blockIdx.x, h = blockIdx.y, b = blockIdx.z;
  __shared__ bf16_t Qs[64][64];
  __shared__ bf16_t Ks[64][64];
  __shared__ bf16_t Vs[64][64];  // [d][m]
  __shared__ bf16_t Ps[64][64];  // [qrow][m]
  int t = threadIdx.x, lane = t & 63, w = t >> 6;
  int quad = lane >> 4, l15 = lane & 15;

  // stage Q
#pragma unroll
  for (int f = 0; f < 2; ++f) {
    int chunk = t + f * 256;
    int row = chunk >> 3, k8 = (chunk & 7) * 8;
    *(bf16x8*)&Qs[row][k8] =
        *(const bf16x8*)&Qb[(size_t)(b * SEQ + qt * 64 + row) * DM + h * DK + k8];
  }
  __syncthreads();
  bf16x8 aq0 = *(const bf16x8*)&Qs[w * 16 + l15][quad * 8];
  bf16x8 aq1 = *(const bf16x8*)&Qs[w * 16 + l15][32 + quad * 8];

  float m_st[4] = {-INFINITY, -INFINITY, -INFINITY, -INFINITY};
  float l_st[4] = {0.f, 0.f, 0.f, 0.f};
  f32x4 o[4] = {};
  const size_t grow0 = (size_t)(b * SEQ + qt * 64 + w * 16) * SEQ;

  for (int mt = 0; mt < 16; ++mt) {
    __syncthreads();  // prev iteration's LDS readers done
#pragma unroll
    for (int f = 0; f < 2; ++f) {
      int chunk = t + f * 256;
      int row = chunk >> 3, k8 = (chunk & 7) * 8;
      *(bf16x8*)&Ks[row][k8] =
          *(const bf16x8*)&Kb[(size_t)(b * SEQ + mt * 64 + row) * DM + h * DK + k8];
      *(bf16x8*)&Vs[row][k8] =
          *(const bf16x8*)&Vt[((size_t)((b * NH + h) * DK + row)) * SEQ + mt * 64 + k8];
    }
    __syncthreads();

    // S = Q K^T  (4 col-tiles of 16)
    f32x4 s[4];
#pragma unroll
    for (int ct = 0; ct < 4; ++ct) {
      bf16x8 bk0 = *(const bf16x8*)&Ks[ct * 16 + l15][quad * 8];
      bf16x8 bk1 = *(const bf16x8*)&Ks[ct * 16 + l15][32 + quad * 8];
      f32x4 z = {};
      s[ct] = mfma16(aq1, bk1, mfma16(aq0, bk0, z));
    }

    // modulate: sv = s/8 * G
    float sv[4][4];  // [ct][r]
#pragma unroll
    for (int r = 0; r < 4; ++r) {
      size_t gr = grow0 + (size_t)(quad * 4 + r) * SEQ + mt * 64;
#pragma unroll
      for (int ct = 0; ct < 4; ++ct) {
        float g = (float)G[gr + ct * 16 + l15];
        sv[ct][r] = s[ct][r] * 0.125f * g;
      }
    }

    // online softmax per row (state replicated across the 16-lane quad)
#pragma unroll
    for (int r = 0; r < 4; ++r) {
      float rm = fmaxf(fmaxf(sv[0][r], sv[1][r]), fmaxf(sv[2][r], sv[3][r]));
#pragma unroll
      for (int off = 1; off < 16; off <<= 1) rm = fmaxf(rm, __shfl_xor(rm, off, 64));
      float mnew = fmaxf(m_st[r], rm);
      float alpha = __expf(m_st[r] - mnew);
      m_st[r] = mnew;
      float p0 = __expf(sv[0][r] - mnew);
      float p1 = __expf(sv[1][r] - mnew);
      float p2 = __expf(sv[2][r] - mnew);
      float p3 = __expf(sv[3][r] - mnew);
      float rs = p0 + p1 + p2 + p3;
#pragma unroll
      for (int off = 1; off < 16; off <<= 1) rs += __shfl_xor(rs, off, 64);
      l_st[r] = l_st[r] * alpha + rs;
#pragma unroll
      for (int ct = 0; ct < 4; ++ct) o[ct][r] *= alpha;
      int prow = w * 16 + quad * 4 + r;
      Ps[prow][0 * 16 + l15] = (bf16_t)p0;
      Ps[prow][1 * 16 + l15] = (bf16_t)p1;
      Ps[prow][2 * 16 + l15] = (bf16_t)p2;
      Ps[prow][3 * 16 + l15] = (bf16_t)p3;
    }
    __syncthreads();  // P visible (cross-lane)

    // O += P V
    bf16x8 ap0 = *(const bf16x8*)&Ps[w * 16 + l15][quad * 8];
    bf16x8 ap1 = *(const bf16x8*)&Ps[w * 16 + l15][32 + quad * 8];
#pragma unroll
    for (int ct = 0; ct < 4; ++ct) {
      bf16x8 bv0 = *(const bf16x8*)&Vs[ct * 16 + l15][quad * 8];
      bf16x8 bv1 = *(const bf16x8*)&Vs[ct * 16 + l15][32 + quad * 8];
      o[ct] = mfma16(ap1, bv1, mfma16(ap0, bv0, o[ct]));
    }
  }

  // epilogue: O /= l, write bf16
#pragma unroll
  for (int r = 0; r < 4; ++r) {
    float inv = 1.0f / l_st[r];
    size_t row = (size_t)(b * SEQ + qt * 64 + w * 16 + quad * 4 + r);
#pragma unroll
    for (int ct = 0; ct < 4; ++ct)
      Ab[row * DM + h * DK + ct * 16 + l15] = (bf16_t)(o[ct][r] * inv);
  }
}

// ---------------------------------------------------------------------------
extern "C" void kernel_launch(void* const* d_in, const int* in_sizes, int n_in,
                              void* d_out, int out_size, void* d_ws, size_t ws_size,
                              hipStream_t stream) {
  const float* query = (const float*)d_in[0];
  const float* key = (const float*)d_in[1];
  const float* value = (const float*)d_in[2];
  const float* wc = (const float*)d_in[3];
  const float* Wq = (const float*)d_in[4];
  const float* bq = (const float*)d_in[5];
  const float* Wk = (const float*)d_in[6];
  const float* bk = (const float*)d_in[7];
  const float* Wv = (const float*)d_in[8];
  const float* bv = (const float*)d_in[9];
  const float* Wo = (const float*)d_in[10];
  const float* bo = (const float*)d_in[11];
  float* out = (float*)d_out;

  bf16_t* Qb = (bf16_t*)d_ws;
  bf16_t* Kb = Qb + (size_t)ROWS * DM;
  bf16_t* Vb = Kb + (size_t)ROWS * DM;
  bf16_t* Vt = Vb + (size_t)ROWS * DM;
  bf16_t* Ab = Vt + (size_t)ROWS * DM;
  bf16_t* G = Ab + (size_t)ROWS * DM;  // 8*1024*1024 bf16

  wc_softmax_kernel<<<BS * SEQ, 256, 0, stream>>>(wc, G);

  dim3 gg(ROWS / 128, DM / 128);
  gemm_mfma<false, false><<<gg, 256, 0, stream>>>(query, Wq, bq, Qb);
  gemm_mfma<false, false><<<gg, 256, 0, stream>>>(key, Wk, bk, Kb);
  gemm_mfma<false, false><<<gg, 256, 0, stream>>>(value, Wv, bv, Vb);

  vtrans_kernel<<<dim3(16, 64), 256, 0, stream>>>(Vb, Vt);

  flash_mfma_kernel<<<dim3(SEQ / 64, NH, BS), 256, 0, stream>>>(Qb, Kb, Vt, G, Ab);

  gemm_mfma<true, true><<<gg, 256, 0, stream>>>(Ab, Wo, bo, out);
}

// Round 5
// 257.370 us; speedup vs baseline: 2.8320x; 1.2253x over previous
//
#include <hip/hip_runtime.h>
#include <math.h>

// Round 5 (R4 resubmit, hardened): R4 aborted at runtime with no locatable
// fault after full address audit. Change vs R4: fused-QKV operand selection
// via indexed pointer arrays (no __restrict__ on selected pointers) instead
// of nested ternaries over restrict-qualified params. All else identical.
//   wc_softmax -> G = 1+softmax(wc) (bf16)
//   gemm_qkv   -> Qb,Kb,Vb (fused via blockIdx.z, 768 blocks)
//   vtrans     -> Vt[bh][d][m]
//   flash_mfma -> Ab  (S^T orientation, wave-private LDS P, K=32 MFMA only)
//   gemm_wo    -> out (BM=64, 512 blocks)

#define BS 8
#define SEQ 1024
#define DM 512
#define NH 8
#define DK 64
#define ROWS (BS * SEQ)

typedef __bf16 bf16_t;
typedef bf16_t bf16x8 __attribute__((ext_vector_type(8)));
typedef bf16_t bf16x4 __attribute__((ext_vector_type(4)));
typedef float f32x4 __attribute__((ext_vector_type(4)));

__device__ inline f32x4 mfma32(bf16x8 a, bf16x8 b, f32x4 c) {
  return __builtin_amdgcn_mfma_f32_16x16x32_bf16(a, b, c, 0, 0, 0);
}

__device__ inline bf16x8 cvt8(float4 a, float4 b) {
  bf16x8 r;
  r[0] = (bf16_t)a.x; r[1] = (bf16_t)a.y; r[2] = (bf16_t)a.z; r[3] = (bf16_t)a.w;
  r[4] = (bf16_t)b.x; r[5] = (bf16_t)b.y; r[6] = (bf16_t)b.z; r[7] = (bf16_t)b.w;
  return r;
}

// ---------------------------------------------------------------------------
// G = 1 + softmax(wc) per row, bf16 out.
// ---------------------------------------------------------------------------
__global__ __launch_bounds__(256) void wc_softmax_kernel(const float* __restrict__ wc,
                                                         bf16_t* __restrict__ G) {
  int row = blockIdx.x;
  const float* x = wc + (size_t)row * SEQ;
  bf16_t* y = G + (size_t)row * SEQ;
  int t = threadIdx.x;
  float4 v = *(const float4*)(x + t * 4);
  float m = fmaxf(fmaxf(v.x, v.y), fmaxf(v.z, v.w));
#pragma unroll
  for (int off = 32; off > 0; off >>= 1) m = fmaxf(m, __shfl_xor(m, off, 64));
  __shared__ float sm[4], ss[4];
  int w = t >> 6;
  if ((t & 63) == 0) sm[w] = m;
  __syncthreads();
  m = fmaxf(fmaxf(sm[0], sm[1]), fmaxf(sm[2], sm[3]));
  float4 e;
  e.x = __expf(v.x - m); e.y = __expf(v.y - m);
  e.z = __expf(v.z - m); e.w = __expf(v.w - m);
  float s = e.x + e.y + e.z + e.w;
#pragma unroll
  for (int off = 32; off > 0; off >>= 1) s += __shfl_xor(s, off, 64);
  if ((t & 63) == 0) ss[w] = s;
  __syncthreads();
  s = ss[0] + ss[1] + ss[2] + ss[3];
  float inv = 1.0f / s;
  bf16x4 g;
  g[0] = (bf16_t)(1.0f + e.x * inv);
  g[1] = (bf16_t)(1.0f + e.y * inv);
  g[2] = (bf16_t)(1.0f + e.z * inv);
  g[3] = (bf16_t)(1.0f + e.w * inv);
  *(bf16x4*)(y + t * 4) = g;
}

// ---------------------------------------------------------------------------
// Fused QKV projections: blockIdx.z selects (X, W, bias, C) via arrays.
// C[8192,512] = X @ W^T + b, fp32 in -> bf16 out.  BM=BN=128, BK=32.
// ---------------------------------------------------------------------------
__global__ __launch_bounds__(256) void gemm_qkv_kernel(
    const float* xq, const float* xk, const float* xv,
    const float* Wq, const float* Wk, const float* Wv,
    const float* bq, const float* bk, const float* bv,
    bf16_t* Cq, bf16_t* Ck, bf16_t* Cv) {
  const float* Xarr[3] = {xq, xk, xv};
  const float* Warr[3] = {Wq, Wk, Wv};
  const float* barr[3] = {bq, bk, bv};
  bf16_t* Carr[3] = {Cq, Ck, Cv};
  int z = blockIdx.z;
  const float* X = Xarr[z];
  const float* W = Warr[z];
  const float* bias = barr[z];
  bf16_t* C = Carr[z];

  __shared__ bf16_t As[128][32];
  __shared__ bf16_t Bs[128][32];
  int t = threadIdx.x;
  int lane = t & 63, w = t >> 6;
  int quad = lane >> 4, l15 = lane & 15;
  int m0w = (w & 1) * 64, n0w = (w >> 1) * 64;
  int mbase = blockIdx.x * 128, nbase = blockIdx.y * 128;
  f32x4 acc[4][4] = {};
  int srow = t >> 1, skoff = (t & 1) * 16;

  for (int kb = 0; kb < DM; kb += 32) {
    const float* p = X + (size_t)(mbase + srow) * DM + kb + skoff;
    float4 x0 = *(const float4*)(p + 0);
    float4 x1 = *(const float4*)(p + 4);
    float4 x2 = *(const float4*)(p + 8);
    float4 x3 = *(const float4*)(p + 12);
    const float* pw = W + (size_t)(nbase + srow) * DM + kb + skoff;
    float4 w0 = *(const float4*)(pw + 0);
    float4 w1 = *(const float4*)(pw + 4);
    float4 w2 = *(const float4*)(pw + 8);
    float4 w3 = *(const float4*)(pw + 12);
    __syncthreads();
    *(bf16x8*)&As[srow][skoff] = cvt8(x0, x1);
    *(bf16x8*)&As[srow][skoff + 8] = cvt8(x2, x3);
    *(bf16x8*)&Bs[srow][skoff] = cvt8(w0, w1);
    *(bf16x8*)&Bs[srow][skoff + 8] = cvt8(w2, w3);
    __syncthreads();
    bf16x8 af[4], bf[4];
#pragma unroll
    for (int mt = 0; mt < 4; ++mt)
      af[mt] = *(const bf16x8*)&As[m0w + mt * 16 + l15][quad * 8];
#pragma unroll
    for (int nt = 0; nt < 4; ++nt)
      bf[nt] = *(const bf16x8*)&Bs[n0w + nt * 16 + l15][quad * 8];
#pragma unroll
    for (int mt = 0; mt < 4; ++mt)
#pragma unroll
      for (int nt = 0; nt < 4; ++nt)
        acc[mt][nt] = mfma32(af[mt], bf[nt], acc[mt][nt]);
  }

#pragma unroll
  for (int nt = 0; nt < 4; ++nt) {
    int col = nbase + n0w + nt * 16 + l15;
    float bc = bias[col];
#pragma unroll
    for (int mt = 0; mt < 4; ++mt)
#pragma unroll
      for (int r = 0; r < 4; ++r) {
        int row = mbase + m0w + mt * 16 + quad * 4 + r;
        C[(size_t)row * DM + col] = (bf16_t)(acc[mt][nt][r] + bc);
      }
  }
}

// ---------------------------------------------------------------------------
// out[8192,512] = Ab(bf16) @ Wo^T + bo, fp32 out.  BM=64, BN=128.
// ---------------------------------------------------------------------------
__global__ __launch_bounds__(256) void gemm_wo_kernel(const bf16_t* __restrict__ X,
                                                      const float* __restrict__ W,
                                                      const float* __restrict__ bias,
                                                      float* __restrict__ C) {
  __shared__ bf16_t As[64][32];
  __shared__ bf16_t Bs[128][32];
  int t = threadIdx.x;
  int lane = t & 63, w = t >> 6;
  int quad = lane >> 4, l15 = lane & 15;
  int m0w = (w & 1) * 32, n0w = (w >> 1) * 64;
  int mbase = blockIdx.x * 64, nbase = blockIdx.y * 128;
  f32x4 acc[2][4] = {};
  int arow = t >> 2, ak8 = (t & 3) * 8;
  int brow = t >> 1, bkoff = (t & 1) * 16;

  for (int kb = 0; kb < DM; kb += 32) {
    bf16x8 xa = *(const bf16x8*)&X[(size_t)(mbase + arow) * DM + kb + ak8];
    const float* pw = W + (size_t)(nbase + brow) * DM + kb + bkoff;
    float4 w0 = *(const float4*)(pw + 0);
    float4 w1 = *(const float4*)(pw + 4);
    float4 w2 = *(const float4*)(pw + 8);
    float4 w3 = *(const float4*)(pw + 12);
    __syncthreads();
    *(bf16x8*)&As[arow][ak8] = xa;
    *(bf16x8*)&Bs[brow][bkoff] = cvt8(w0, w1);
    *(bf16x8*)&Bs[brow][bkoff + 8] = cvt8(w2, w3);
    __syncthreads();
    bf16x8 af[2], bf[4];
#pragma unroll
    for (int mt = 0; mt < 2; ++mt)
      af[mt] = *(const bf16x8*)&As[m0w + mt * 16 + l15][quad * 8];
#pragma unroll
    for (int nt = 0; nt < 4; ++nt)
      bf[nt] = *(const bf16x8*)&Bs[n0w + nt * 16 + l15][quad * 8];
#pragma unroll
    for (int mt = 0; mt < 2; ++mt)
#pragma unroll
      for (int nt = 0; nt < 4; ++nt)
        acc[mt][nt] = mfma32(af[mt], bf[nt], acc[mt][nt]);
  }

#pragma unroll
  for (int nt = 0; nt < 4; ++nt) {
    int col = nbase + n0w + nt * 16 + l15;
    float bc = bias[col];
#pragma unroll
    for (int mt = 0; mt < 2; ++mt)
#pragma unroll
      for (int r = 0; r < 4; ++r) {
        int row = mbase + m0w + mt * 16 + quad * 4 + r;
        C[(size_t)row * DM + col] = acc[mt][nt][r] + bc;
      }
  }
}

// ---------------------------------------------------------------------------
// Vt[(b*8+h)*64 + d][m] = Vb[b*1024 + m][h*64 + d]
// ---------------------------------------------------------------------------
__global__ __launch_bounds__(256) void vtrans_kernel(const bf16_t* __restrict__ Vb,
                                                     bf16_t* __restrict__ Vt) {
  int mt = blockIdx.x;
  int bh = blockIdx.y;
  int b = bh >> 3, h = bh & 7;
  __shared__ bf16_t Ts[64][66];
  int t = threadIdx.x;
#pragma unroll
  for (int f = 0; f < 2; ++f) {
    int chunk = t + f * 256;
    int row = chunk >> 3;
    int c8 = (chunk & 7) * 8;
    bf16x8 v = *(const bf16x8*)&Vb[(size_t)(b * SEQ + mt * 64 + row) * DM + h * DK + c8];
#pragma unroll
    for (int j = 0; j < 8; ++j) Ts[c8 + j][row] = v[j];
  }
  __syncthreads();
#pragma unroll
  for (int f = 0; f < 2; ++f) {
    int chunk = t + f * 256;
    int d = chunk >> 3;
    int m8 = (chunk & 7) * 8;
    bf16x8 o;
#pragma unroll
    for (int j = 0; j < 8; ++j) o[j] = Ts[d][m8 + j];
    *(bf16x8*)&Vt[((size_t)(bh * DK + d)) * SEQ + mt * 64 + m8] = o;
  }
}

// ---------------------------------------------------------------------------
// Flash attention.  Per block: 64 q-rows x (h, b); 4 waves, 16 q each.
// S^T = mfma32(K_frag, Q_frag): lane(quad,l15) reg r = S[kv=ct*16+quad*4+r][q=l15]
// -> softmax state per q=l15 (xor-16/32 shuffles only)
// -> P to wave-private Ps[q][kv] rows (b64 writes; per-wave DS ordering means
//    no barrier needed), read back as K=32 B-frags (b128);
//    O^T[d][q] += V^T[d][kv] P^T[kv][q].
// ---------------------------------------------------------------------------
__global__ __launch_bounds__(256) void flash_mfma_kernel(const bf16_t* __restrict__ Qb,
                                                         const bf16_t* __restrict__ Kb,
                                                         const bf16_t* __restrict__ Vt,
                                                         const bf16_t* __restrict__ G,
                                                         bf16_t* __restrict__ Ab) {
  int qt = blockIdx.x, h = blockIdx.y, b = blockIdx.z;
  __shared__ bf16_t Qs[64][72];
  __shared__ bf16_t Ks[64][72];
  __shared__ bf16_t Vs[64][72];  // [d][kv]
  __shared__ bf16_t Ps[64][72];  // [q][kv], rows wave-private
  int t = threadIdx.x, lane = t & 63, w = t >> 6;
  int quad = lane >> 4, l15 = lane & 15;

  // stage Q once
#pragma unroll
  for (int f = 0; f < 2; ++f) {
    int chunk = t + f * 256;
    int row = chunk >> 3, k8 = (chunk & 7) * 8;
    *(bf16x8*)&Qs[row][k8] =
        *(const bf16x8*)&Qb[(size_t)(b * SEQ + qt * 64 + row) * DM + h * DK + k8];
  }
  __syncthreads();
  bf16x8 aq0 = *(const bf16x8*)&Qs[w * 16 + l15][quad * 8];  // B: Q[q=l15][d]
  bf16x8 aq1 = *(const bf16x8*)&Qs[w * 16 + l15][32 + quad * 8];

  float m_st = -INFINITY, l_st = 0.f;  // per q = l15 (replicated over quads)
  f32x4 o[4] = {};                     // o[dt]: O^T rows d=dt*16+quad*4+reg, col q=l15
  const size_t grow = (size_t)(b * SEQ + qt * 64 + w * 16 + l15) * SEQ;

  for (int mt = 0; mt < 16; ++mt) {
    __syncthreads();
#pragma unroll
    for (int f = 0; f < 2; ++f) {
      int chunk = t + f * 256;
      int row = chunk >> 3, k8 = (chunk & 7) * 8;
      *(bf16x8*)&Ks[row][k8] =
          *(const bf16x8*)&Kb[(size_t)(b * SEQ + mt * 64 + row) * DM + h * DK + k8];
      *(bf16x8*)&Vs[row][k8] =
          *(const bf16x8*)&Vt[((size_t)((b * NH + h) * DK + row)) * SEQ + mt * 64 + k8];
    }
    __syncthreads();

    // S^T: D[m=kv][n=q]
    f32x4 s[4];
#pragma unroll
    for (int ct = 0; ct < 4; ++ct) {
      bf16x8 ak0 = *(const bf16x8*)&Ks[ct * 16 + l15][quad * 8];
      bf16x8 ak1 = *(const bf16x8*)&Ks[ct * 16 + l15][32 + quad * 8];
      f32x4 z = {};
      s[ct] = mfma32(ak1, aq1, mfma32(ak0, aq0, z));
    }

    // modulate: sv = s/8 * G[q][kv]; kv = mt*64 + ct*16 + quad*4 + r
    float sv[4][4];
    float rm = -INFINITY;
#pragma unroll
    for (int ct = 0; ct < 4; ++ct) {
      bf16x4 g4 = *(const bf16x4*)&G[grow + mt * 64 + ct * 16 + quad * 4];
#pragma unroll
      for (int r = 0; r < 4; ++r) {
        float x = s[ct][r] * 0.125f * (float)g4[r];
        sv[ct][r] = x;
        rm = fmaxf(rm, x);
      }
    }
    rm = fmaxf(rm, __shfl_xor(rm, 16, 64));
    rm = fmaxf(rm, __shfl_xor(rm, 32, 64));
    float mnew = fmaxf(m_st, rm);
    float alpha = __expf(m_st - mnew);
    m_st = mnew;

    float rs = 0.f;
#pragma unroll
    for (int ct = 0; ct < 4; ++ct) {
      bf16x4 pb;
#pragma unroll
      for (int r = 0; r < 4; ++r) {
        float p = __expf(sv[ct][r] - mnew);
        pb[r] = (bf16_t)p;
        rs += p;
      }
      *(bf16x4*)&Ps[w * 16 + l15][ct * 16 + quad * 4] = pb;  // wave-private row
    }
    rs += __shfl_xor(rs, 16, 64);
    rs += __shfl_xor(rs, 32, 64);
    l_st = l_st * alpha + rs;

#pragma unroll
    for (int dt = 0; dt < 4; ++dt) {
      o[dt][0] *= alpha; o[dt][1] *= alpha; o[dt][2] *= alpha; o[dt][3] *= alpha;
    }
    // O^T += V^T P^T  (K=32 x2; DS ops are wave-ordered, no barrier)
#pragma unroll
    for (int c = 0; c < 2; ++c) {
      bf16x8 bp = *(const bf16x8*)&Ps[w * 16 + l15][c * 32 + quad * 8];
#pragma unroll
      for (int dt = 0; dt < 4; ++dt) {
        bf16x8 av = *(const bf16x8*)&Vs[dt * 16 + l15][c * 32 + quad * 8];
        o[dt] = mfma32(av, bp, o[dt]);
      }
    }
  }

  // epilogue
  float linv = 1.0f / l_st;
  size_t qrow = (size_t)(b * SEQ + qt * 64 + w * 16 + l15);
#pragma unroll
  for (int dt = 0; dt < 4; ++dt)
#pragma unroll
    for (int r = 0; r < 4; ++r)
      Ab[qrow * DM + h * DK + dt * 16 + quad * 4 + r] = (bf16_t)(o[dt][r] * linv);
}

// ---------------------------------------------------------------------------
extern "C" void kernel_launch(void* const* d_in, const int* in_sizes, int n_in,
                              void* d_out, int out_size, void* d_ws, size_t ws_size,
                              hipStream_t stream) {
  const float* query = (const float*)d_in[0];
  const float* key = (const float*)d_in[1];
  const float* value = (const float*)d_in[2];
  const float* wc = (const float*)d_in[3];
  const float* Wq = (const float*)d_in[4];
  const float* bq = (const float*)d_in[5];
  const float* Wk = (const float*)d_in[6];
  const float* bk = (const float*)d_in[7];
  const float* Wv = (const float*)d_in[8];
  const float* bv = (const float*)d_in[9];
  const float* Wo = (const float*)d_in[10];
  const float* bo = (const float*)d_in[11];
  float* out = (float*)d_out;

  bf16_t* Qb = (bf16_t*)d_ws;
  bf16_t* Kb = Qb + (size_t)ROWS * DM;
  bf16_t* Vb = Kb + (size_t)ROWS * DM;
  bf16_t* Vt = Vb + (size_t)ROWS * DM;
  bf16_t* Ab = Vt + (size_t)ROWS * DM;
  bf16_t* G = Ab + (size_t)ROWS * DM;

  wc_softmax_kernel<<<BS * SEQ, 256, 0, stream>>>(wc, G);

  gemm_qkv_kernel<<<dim3(ROWS / 128, DM / 128, 3), 256, 0, stream>>>(
      query, key, value, Wq, Wk, Wv, bq, bk, bv, Qb, Kb, Vb);

  vtrans_kernel<<<dim3(16, 64), 256, 0, stream>>>(Vb, Vt);

  flash_mfma_kernel<<<dim3(SEQ / 64, NH, BS), 256, 0, stream>>>(Qb, Kb, Vt, G, Ab);

  gemm_wo_kernel<<<dim3(ROWS / 64, DM / 128), 256, 0, stream>>>(Ab, Wo, bo, out);
}

// Round 6
// 241.330 us; speedup vs baseline: 3.0202x; 1.0665x over previous
//
#include <hip/hip_runtime.h>
#include <math.h>

// Round 6: GEMM overhaul (flash/wc_softmax/vtrans byte-identical to R5).
//   cvt        -> Xq,Xk,Xv,Wqb,Wkb,Wvb,Wob bf16 (one fused elementwise pass)
//   wc_softmax -> G = 1+softmax(wc) (bf16)
//   gemm (m97-style: global_load_lds 16B staging, BK=32, pure bf16 tiles)
//              -> Qb,Kb,Vb (fused z, 768 blocks) ; out = Ab@Wo^T+bo (512 blocks)
//   vtrans     -> Vt[bh][d][m]
//   flash_mfma -> Ab
// ws: 12x 4.19M + 4x 0.26M + 8.39M bf16 ~= 86 MB.

#define BS 8
#define SEQ 1024
#define DM 512
#define NH 8
#define DK 64
#define ROWS (BS * SEQ)

typedef __bf16 bf16_t;
typedef bf16_t bf16x8 __attribute__((ext_vector_type(8)));
typedef bf16_t bf16x4 __attribute__((ext_vector_type(4)));
typedef float f32x4 __attribute__((ext_vector_type(4)));

__device__ inline f32x4 mfma32(bf16x8 a, bf16x8 b, f32x4 c) {
  return __builtin_amdgcn_mfma_f32_16x16x32_bf16(a, b, c, 0, 0, 0);
}

// async global->LDS, 16 bytes/lane.  LDS dest = wave-uniform base + lane*16.
__device__ inline void gload_lds16(const bf16_t* g, bf16_t* l) {
  __builtin_amdgcn_global_load_lds(
      (const __attribute__((address_space(1))) void*)g,
      (__attribute__((address_space(3))) void*)l, 16, 0, 0);
}

// ---------------------------------------------------------------------------
// Fused fp32 -> bf16 conversion for 3 activations (512 blocks each) and
// 4 weight matrices (32 blocks each).  8192 elements per block.
// ---------------------------------------------------------------------------
__global__ __launch_bounds__(256) void cvt_kernel(
    const float* q, const float* k, const float* v,
    const float* wq, const float* wk, const float* wv, const float* wo,
    bf16_t* xq, bf16_t* xk, bf16_t* xv,
    bf16_t* wqb, bf16_t* wkb, bf16_t* wvb, bf16_t* wob) {
  const float* srcs[7] = {q, k, v, wq, wk, wv, wo};
  bf16_t* dsts[7] = {xq, xk, xv, wqb, wkb, wvb, wob};
  int b = blockIdx.x;
  int seg, boff;
  if (b < 1536) { seg = b >> 9; boff = b & 511; }
  else { seg = 3 + ((b - 1536) >> 5); boff = (b - 1536) & 31; }
  const float* src = srcs[seg] + (size_t)boff * 8192;
  bf16_t* dst = dsts[seg] + (size_t)boff * 8192;
  int t = threadIdx.x;
#pragma unroll
  for (int f = 0; f < 8; ++f) {
    int idx = (f * 256 + t) * 4;
    float4 x = *(const float4*)(src + idx);
    bf16x4 o;
    o[0] = (bf16_t)x.x; o[1] = (bf16_t)x.y; o[2] = (bf16_t)x.z; o[3] = (bf16_t)x.w;
    *(bf16x4*)(dst + idx) = o;
  }
}

// ---------------------------------------------------------------------------
// G = 1 + softmax(wc) per row, bf16 out.
// ---------------------------------------------------------------------------
__global__ __launch_bounds__(256) void wc_softmax_kernel(const float* __restrict__ wc,
                                                         bf16_t* __restrict__ G) {
  int row = blockIdx.x;
  const float* x = wc + (size_t)row * SEQ;
  bf16_t* y = G + (size_t)row * SEQ;
  int t = threadIdx.x;
  float4 v = *(const float4*)(x + t * 4);
  float m = fmaxf(fmaxf(v.x, v.y), fmaxf(v.z, v.w));
#pragma unroll
  for (int off = 32; off > 0; off >>= 1) m = fmaxf(m, __shfl_xor(m, off, 64));
  __shared__ float sm[4], ss[4];
  int w = t >> 6;
  if ((t & 63) == 0) sm[w] = m;
  __syncthreads();
  m = fmaxf(fmaxf(sm[0], sm[1]), fmaxf(sm[2], sm[3]));
  float4 e;
  e.x = __expf(v.x - m); e.y = __expf(v.y - m);
  e.z = __expf(v.z - m); e.w = __expf(v.w - m);
  float s = e.x + e.y + e.z + e.w;
#pragma unroll
  for (int off = 32; off > 0; off >>= 1) s += __shfl_xor(s, off, 64);
  if ((t & 63) == 0) ss[w] = s;
  __syncthreads();
  s = ss[0] + ss[1] + ss[2] + ss[3];
  float inv = 1.0f / s;
  bf16x4 g;
  g[0] = (bf16_t)(1.0f + e.x * inv);
  g[1] = (bf16_t)(1.0f + e.y * inv);
  g[2] = (bf16_t)(1.0f + e.z * inv);
  g[3] = (bf16_t)(1.0f + e.w * inv);
  *(bf16x4*)(y + t * 4) = g;
}

// ---------------------------------------------------------------------------
// Core bf16 GEMM: C[M,512] = X @ W^T + bias.  BN=128, BK=32, BM in {64,128}.
// Staging via global_load_lds (16B/lane): wave-instr i=f*4+w covers rows
// i*16 + lane/4, k byte-offset (lane&3)*16; LDS dest uniform As+i*512.
// ---------------------------------------------------------------------------
template <int BM, bool OUTF32>
__device__ inline void gemm_core(const bf16_t* X, const bf16_t* W,
                                 const float* bias, void* Cv,
                                 int mblk, int nblk) {
  __shared__ bf16_t As[BM * 32];
  __shared__ bf16_t Bs[128 * 32];
  int t = threadIdx.x, lane = t & 63, w = t >> 6;
  int quad = lane >> 4, l15 = lane & 15;
  constexpr int MT = BM / 32;           // m-tiles per wave (4 or 2)
  int m0w = (w & 1) * (BM / 2), n0w = (w >> 1) * 64;
  int mbase = mblk * BM, nbase = nblk * 128;
  int lr = lane >> 2, l4 = lane & 3;    // staging row/col-group
  f32x4 acc[MT][4] = {};

  for (int kb = 0; kb < DM; kb += 32) {
    __syncthreads();  // previous tile's readers done
#pragma unroll
    for (int f = 0; f < BM / 64; ++f) {
      int i = f * 4 + w;
      gload_lds16(X + (size_t)(mbase + i * 16 + lr) * DM + kb + l4 * 8, As + i * 512);
    }
#pragma unroll
    for (int f = 0; f < 2; ++f) {
      int i = f * 4 + w;
      gload_lds16(W + (size_t)(nbase + i * 16 + lr) * DM + kb + l4 * 8, Bs + i * 512);
    }
    __syncthreads();  // drains vmcnt -> staged tiles visible
    bf16x8 af[MT], bf[4];
#pragma unroll
    for (int mt = 0; mt < MT; ++mt)
      af[mt] = *(const bf16x8*)&As[(m0w + mt * 16 + l15) * 32 + quad * 8];
#pragma unroll
    for (int nt = 0; nt < 4; ++nt)
      bf[nt] = *(const bf16x8*)&Bs[(n0w + nt * 16 + l15) * 32 + quad * 8];
#pragma unroll
    for (int mt = 0; mt < MT; ++mt)
#pragma unroll
      for (int nt = 0; nt < 4; ++nt)
        acc[mt][nt] = mfma32(af[mt], bf[nt], acc[mt][nt]);
  }

#pragma unroll
  for (int nt = 0; nt < 4; ++nt) {
    int col = nbase + n0w + nt * 16 + l15;
    float bc = bias[col];
#pragma unroll
    for (int mt = 0; mt < MT; ++mt)
#pragma unroll
      for (int r = 0; r < 4; ++r) {
        int row = mbase + m0w + mt * 16 + quad * 4 + r;
        float vv = acc[mt][nt][r] + bc;
        if (OUTF32)
          ((float*)Cv)[(size_t)row * DM + col] = vv;
        else
          ((bf16_t*)Cv)[(size_t)row * DM + col] = (bf16_t)vv;
      }
  }
}

// Fused QKV: blockIdx.z selects operands via arrays (R5-safe pattern).
__global__ __launch_bounds__(256) void gemm_qkv_kernel(
    const bf16_t* xq, const bf16_t* xk, const bf16_t* xv,
    const bf16_t* wq, const bf16_t* wk, const bf16_t* wv,
    const float* bq, const float* bk, const float* bv,
    bf16_t* cq, bf16_t* ck, bf16_t* cv) {
  const bf16_t* Xarr[3] = {xq, xk, xv};
  const bf16_t* Warr[3] = {wq, wk, wv};
  const float* barr[3] = {bq, bk, bv};
  bf16_t* Carr[3] = {cq, ck, cv};
  int z = blockIdx.z;
  gemm_core<128, false>(Xarr[z], Warr[z], barr[z], Carr[z], blockIdx.x, blockIdx.y);
}

__global__ __launch_bounds__(256) void gemm_wo_kernel(const bf16_t* X, const bf16_t* W,
                                                      const float* bias, float* C) {
  gemm_core<64, true>(X, W, bias, C, blockIdx.x, blockIdx.y);
}

// ---------------------------------------------------------------------------
// Vt[(b*8+h)*64 + d][m] = Vb[b*1024 + m][h*64 + d]
// ---------------------------------------------------------------------------
__global__ __launch_bounds__(256) void vtrans_kernel(const bf16_t* __restrict__ Vb,
                                                     bf16_t* __restrict__ Vt) {
  int mt = blockIdx.x;
  int bh = blockIdx.y;
  int b = bh >> 3, h = bh & 7;
  __shared__ bf16_t Ts[64][66];
  int t = threadIdx.x;
#pragma unroll
  for (int f = 0; f < 2; ++f) {
    int chunk = t + f * 256;
    int row = chunk >> 3;
    int c8 = (chunk & 7) * 8;
    bf16x8 v = *(const bf16x8*)&Vb[(size_t)(b * SEQ + mt * 64 + row) * DM + h * DK + c8];
#pragma unroll
    for (int j = 0; j < 8; ++j) Ts[c8 + j][row] = v[j];
  }
  __syncthreads();
#pragma unroll
  for (int f = 0; f < 2; ++f) {
    int chunk = t + f * 256;
    int d = chunk >> 3;
    int m8 = (chunk & 7) * 8;
    bf16x8 o;
#pragma unroll
    for (int j = 0; j < 8; ++j) o[j] = Ts[d][m8 + j];
    *(bf16x8*)&Vt[((size_t)(bh * DK + d)) * SEQ + mt * 64 + m8] = o;
  }
}

// ---------------------------------------------------------------------------
// Flash attention (byte-identical to R5).
// ---------------------------------------------------------------------------
__global__ __launch_bounds__(256) void flash_mfma_kernel(const bf16_t* __restrict__ Qb,
                                                         const bf16_t* __restrict__ Kb,
                                                         const bf16_t* __restrict__ Vt,
                                                         const bf16_t* __restrict__ G,
                                                         bf16_t* __restrict__ Ab) {
  int qt = blockIdx.x, h = blockIdx.y, b = blockIdx.z;
  __shared__ bf16_t Qs[64][72];
  __shared__ bf16_t Ks[64][72];
  __shared__ bf16_t Vs[64][72];  // [d][kv]
  __shared__ bf16_t Ps[64][72];  // [q][kv], rows wave-private
  int t = threadIdx.x, lane = t & 63, w = t >> 6;
  int quad = lane >> 4, l15 = lane & 15;

#pragma unroll
  for (int f = 0; f < 2; ++f) {
    int chunk = t + f * 256;
    int row = chunk >> 3, k8 = (chunk & 7) * 8;
    *(bf16x8*)&Qs[row][k8] =
        *(const bf16x8*)&Qb[(size_t)(b * SEQ + qt * 64 + row) * DM + h * DK + k8];
  }
  __syncthreads();
  bf16x8 aq0 = *(const bf16x8*)&Qs[w * 16 + l15][quad * 8];
  bf16x8 aq1 = *(const bf16x8*)&Qs[w * 16 + l15][32 + quad * 8];

  float m_st = -INFINITY, l_st = 0.f;
  f32x4 o[4] = {};
  const size_t grow = (size_t)(b * SEQ + qt * 64 + w * 16 + l15) * SEQ;

  for (int mt = 0; mt < 16; ++mt) {
    __syncthreads();
#pragma unroll
    for (int f = 0; f < 2; ++f) {
      int chunk = t + f * 256;
      int row = chunk >> 3, k8 = (chunk & 7) * 8;
      *(bf16x8*)&Ks[row][k8] =
          *(const bf16x8*)&Kb[(size_t)(b * SEQ + mt * 64 + row) * DM + h * DK + k8];
      *(bf16x8*)&Vs[row][k8] =
          *(const bf16x8*)&Vt[((size_t)((b * NH + h) * DK + row)) * SEQ + mt * 64 + k8];
    }
    __syncthreads();

    f32x4 s[4];
#pragma unroll
    for (int ct = 0; ct < 4; ++ct) {
      bf16x8 ak0 = *(const bf16x8*)&Ks[ct * 16 + l15][quad * 8];
      bf16x8 ak1 = *(const bf16x8*)&Ks[ct * 16 + l15][32 + quad * 8];
      f32x4 z = {};
      s[ct] = mfma32(ak1, aq1, mfma32(ak0, aq0, z));
    }

    float sv[4][4];
    float rm = -INFINITY;
#pragma unroll
    for (int ct = 0; ct < 4; ++ct) {
      bf16x4 g4 = *(const bf16x4*)&G[grow + mt * 64 + ct * 16 + quad * 4];
#pragma unroll
      for (int r = 0; r < 4; ++r) {
        float x = s[ct][r] * 0.125f * (float)g4[r];
        sv[ct][r] = x;
        rm = fmaxf(rm, x);
      }
    }
    rm = fmaxf(rm, __shfl_xor(rm, 16, 64));
    rm = fmaxf(rm, __shfl_xor(rm, 32, 64));
    float mnew = fmaxf(m_st, rm);
    float alpha = __expf(m_st - mnew);
    m_st = mnew;

    float rs = 0.f;
#pragma unroll
    for (int ct = 0; ct < 4; ++ct) {
      bf16x4 pb;
#pragma unroll
      for (int r = 0; r < 4; ++r) {
        float p = __expf(sv[ct][r] - mnew);
        pb[r] = (bf16_t)p;
        rs += p;
      }
      *(bf16x4*)&Ps[w * 16 + l15][ct * 16 + quad * 4] = pb;
    }
    rs += __shfl_xor(rs, 16, 64);
    rs += __shfl_xor(rs, 32, 64);
    l_st = l_st * alpha + rs;

#pragma unroll
    for (int dt = 0; dt < 4; ++dt) {
      o[dt][0] *= alpha; o[dt][1] *= alpha; o[dt][2] *= alpha; o[dt][3] *= alpha;
    }
#pragma unroll
    for (int c = 0; c < 2; ++c) {
      bf16x8 bp = *(const bf16x8*)&Ps[w * 16 + l15][c * 32 + quad * 8];
#pragma unroll
      for (int dt = 0; dt < 4; ++dt) {
        bf16x8 av = *(const bf16x8*)&Vs[dt * 16 + l15][c * 32 + quad * 8];
        o[dt] = mfma32(av, bp, o[dt]);
      }
    }
  }

  float linv = 1.0f / l_st;
  size_t qrow = (size_t)(b * SEQ + qt * 64 + w * 16 + l15);
#pragma unroll
  for (int dt = 0; dt < 4; ++dt)
#pragma unroll
    for (int r = 0; r < 4; ++r)
      Ab[qrow * DM + h * DK + dt * 16 + quad * 4 + r] = (bf16_t)(o[dt][r] * linv);
}

// ---------------------------------------------------------------------------
extern "C" void kernel_launch(void* const* d_in, const int* in_sizes, int n_in,
                              void* d_out, int out_size, void* d_ws, size_t ws_size,
                              hipStream_t stream) {
  const float* query = (const float*)d_in[0];
  const float* key = (const float*)d_in[1];
  const float* value = (const float*)d_in[2];
  const float* wc = (const float*)d_in[3];
  const float* Wq = (const float*)d_in[4];
  const float* bq = (const float*)d_in[5];
  const float* Wk = (const float*)d_in[6];
  const float* bk = (const float*)d_in[7];
  const float* Wv = (const float*)d_in[8];
  const float* bv = (const float*)d_in[9];
  const float* Wo = (const float*)d_in[10];
  const float* bo = (const float*)d_in[11];
  float* out = (float*)d_out;

  const size_t ACT = (size_t)ROWS * DM;  // 4.19M
  const size_t WSZ = (size_t)DM * DM;    // 262K
  bf16_t* Qb = (bf16_t*)d_ws;
  bf16_t* Kb = Qb + ACT;
  bf16_t* Vb = Kb + ACT;
  bf16_t* Vt = Vb + ACT;
  bf16_t* Ab = Vt + ACT;
  bf16_t* G = Ab + ACT;            // 8.39M
  bf16_t* Xq = G + (size_t)BS * SEQ * SEQ;
  bf16_t* Xk = Xq + ACT;
  bf16_t* Xv = Xk + ACT;
  bf16_t* Wqb = Xv + ACT;
  bf16_t* Wkb = Wqb + WSZ;
  bf16_t* Wvb = Wkb + WSZ;
  bf16_t* Wob = Wvb + WSZ;

  cvt_kernel<<<1664, 256, 0, stream>>>(query, key, value, Wq, Wk, Wv, Wo,
                                       Xq, Xk, Xv, Wqb, Wkb, Wvb, Wob);

  wc_softmax_kernel<<<BS * SEQ, 256, 0, stream>>>(wc, G);

  gemm_qkv_kernel<<<dim3(ROWS / 128, DM / 128, 3), 256, 0, stream>>>(
      Xq, Xk, Xv, Wqb, Wkb, Wvb, bq, bk, bv, Qb, Kb, Vb);

  vtrans_kernel<<<dim3(16, 64), 256, 0, stream>>>(Vb, Vt);

  flash_mfma_kernel<<<dim3(SEQ / 64, NH, BS), 256, 0, stream>>>(Qb, Kb, Vt, G, Ab);

  gemm_wo_kernel<<<dim3(ROWS / 64, DM / 128), 256, 0, stream>>>(Ab, Wob, bo, out);
}

// Round 7
// 230.018 us; speedup vs baseline: 3.1687x; 1.0492x over previous
//
#include <hip/hip_runtime.h>
#include <math.h>

// Round 7: software-pipelined load latency.
//   gemm: LDS double-buffer + global_load_lds prefetch, ONE barrier/iter
//         (prefetch for i+1 issued before compute(i) -> MFMA covers latency;
//          barrier's vmcnt(0) drain is cheap because loads are old).
//   flash: staging regs hoisted -- K/V(mt+1) + G(mt+1) loaded into VGPRs
//          during compute(mt); ds_write at iter top hits completed loads.
//   cvt / wc_softmax / vtrans unchanged from R6.

#define BS 8
#define SEQ 1024
#define DM 512
#define NH 8
#define DK 64
#define ROWS (BS * SEQ)

typedef __bf16 bf16_t;
typedef bf16_t bf16x8 __attribute__((ext_vector_type(8)));
typedef bf16_t bf16x4 __attribute__((ext_vector_type(4)));
typedef float f32x4 __attribute__((ext_vector_type(4)));

__device__ inline f32x4 mfma32(bf16x8 a, bf16x8 b, f32x4 c) {
  return __builtin_amdgcn_mfma_f32_16x16x32_bf16(a, b, c, 0, 0, 0);
}

// async global->LDS, 16 bytes/lane.  LDS dest = wave-uniform base + lane*16.
__device__ inline void gload_lds16(const bf16_t* g, bf16_t* l) {
  __builtin_amdgcn_global_load_lds(
      (const __attribute__((address_space(1))) void*)g,
      (__attribute__((address_space(3))) void*)l, 16, 0, 0);
}

// ---------------------------------------------------------------------------
// Fused fp32 -> bf16 conversion: 3 activations (512 blocks each), 4 weights
// (32 blocks each).  8192 elements per block.
// ---------------------------------------------------------------------------
__global__ __launch_bounds__(256) void cvt_kernel(
    const float* q, const float* k, const float* v,
    const float* wq, const float* wk, const float* wv, const float* wo,
    bf16_t* xq, bf16_t* xk, bf16_t* xv,
    bf16_t* wqb, bf16_t* wkb, bf16_t* wvb, bf16_t* wob) {
  const float* srcs[7] = {q, k, v, wq, wk, wv, wo};
  bf16_t* dsts[7] = {xq, xk, xv, wqb, wkb, wvb, wob};
  int b = blockIdx.x;
  int seg, boff;
  if (b < 1536) { seg = b >> 9; boff = b & 511; }
  else { seg = 3 + ((b - 1536) >> 5); boff = (b - 1536) & 31; }
  const float* src = srcs[seg] + (size_t)boff * 8192;
  bf16_t* dst = dsts[seg] + (size_t)boff * 8192;
  int t = threadIdx.x;
#pragma unroll
  for (int f = 0; f < 8; ++f) {
    int idx = (f * 256 + t) * 4;
    float4 x = *(const float4*)(src + idx);
    bf16x4 o;
    o[0] = (bf16_t)x.x; o[1] = (bf16_t)x.y; o[2] = (bf16_t)x.z; o[3] = (bf16_t)x.w;
    *(bf16x4*)(dst + idx) = o;
  }
}

// ---------------------------------------------------------------------------
// G = 1 + softmax(wc) per row, bf16 out.
// ---------------------------------------------------------------------------
__global__ __launch_bounds__(256) void wc_softmax_kernel(const float* __restrict__ wc,
                                                         bf16_t* __restrict__ G) {
  int row = blockIdx.x;
  const float* x = wc + (size_t)row * SEQ;
  bf16_t* y = G + (size_t)row * SEQ;
  int t = threadIdx.x;
  float4 v = *(const float4*)(x + t * 4);
  float m = fmaxf(fmaxf(v.x, v.y), fmaxf(v.z, v.w));
#pragma unroll
  for (int off = 32; off > 0; off >>= 1) m = fmaxf(m, __shfl_xor(m, off, 64));
  __shared__ float sm[4], ss[4];
  int w = t >> 6;
  if ((t & 63) == 0) sm[w] = m;
  __syncthreads();
  m = fmaxf(fmaxf(sm[0], sm[1]), fmaxf(sm[2], sm[3]));
  float4 e;
  e.x = __expf(v.x - m); e.y = __expf(v.y - m);
  e.z = __expf(v.z - m); e.w = __expf(v.w - m);
  float s = e.x + e.y + e.z + e.w;
#pragma unroll
  for (int off = 32; off > 0; off >>= 1) s += __shfl_xor(s, off, 64);
  if ((t & 63) == 0) ss[w] = s;
  __syncthreads();
  s = ss[0] + ss[1] + ss[2] + ss[3];
  float inv = 1.0f / s;
  bf16x4 g;
  g[0] = (bf16_t)(1.0f + e.x * inv);
  g[1] = (bf16_t)(1.0f + e.y * inv);
  g[2] = (bf16_t)(1.0f + e.z * inv);
  g[3] = (bf16_t)(1.0f + e.w * inv);
  *(bf16x4*)(y + t * 4) = g;
}

// ---------------------------------------------------------------------------
// Core bf16 GEMM: C[M,512] = X @ W^T + bias.  BN=128, BK=32, BM in {64,128}.
// LDS double-buffered; global_load_lds prefetch for iter i+1 issued before
// compute(i); single barrier per iteration.
// ---------------------------------------------------------------------------
template <int BM, bool OUTF32>
__device__ inline void gemm_core(const bf16_t* X, const bf16_t* W,
                                 const float* bias, void* Cv,
                                 int mblk, int nblk) {
  __shared__ bf16_t As[2][BM * 32];
  __shared__ bf16_t Bs[2][128 * 32];
  int t = threadIdx.x, lane = t & 63, w = t >> 6;
  int quad = lane >> 4, l15 = lane & 15;
  constexpr int MT = BM / 32;
  int m0w = (w & 1) * (BM / 2), n0w = (w >> 1) * 64;
  int mbase = mblk * BM, nbase = nblk * 128;
  int lr = lane >> 2, l4 = lane & 3;
  f32x4 acc[MT][4] = {};

  // prologue: stage k-block 0 into buffer 0
#pragma unroll
  for (int f = 0; f < BM / 64; ++f) {
    int i = f * 4 + w;
    gload_lds16(X + (size_t)(mbase + i * 16 + lr) * DM + l4 * 8, &As[0][i * 512]);
  }
#pragma unroll
  for (int f = 0; f < 2; ++f) {
    int i = f * 4 + w;
    gload_lds16(W + (size_t)(nbase + i * 16 + lr) * DM + l4 * 8, &Bs[0][i * 512]);
  }

  for (int it = 0; it < 16; ++it) {
    __syncthreads();  // drain own gloads (issued last iter -> cheap), publish buf[it&1]
    int cb = it & 1;
    if (it + 1 < 16) {
      int kb = (it + 1) * 32, nb = (it + 1) & 1;
#pragma unroll
      for (int f = 0; f < BM / 64; ++f) {
        int i = f * 4 + w;
        gload_lds16(X + (size_t)(mbase + i * 16 + lr) * DM + kb + l4 * 8, &As[nb][i * 512]);
      }
#pragma unroll
      for (int f = 0; f < 2; ++f) {
        int i = f * 4 + w;
        gload_lds16(W + (size_t)(nbase + i * 16 + lr) * DM + kb + l4 * 8, &Bs[nb][i * 512]);
      }
    }
    bf16x8 af[MT], bfr[4];
#pragma unroll
    for (int mt = 0; mt < MT; ++mt)
      af[mt] = *(const bf16x8*)&As[cb][(m0w + mt * 16 + l15) * 32 + quad * 8];
#pragma unroll
    for (int nt = 0; nt < 4; ++nt)
      bfr[nt] = *(const bf16x8*)&Bs[cb][(n0w + nt * 16 + l15) * 32 + quad * 8];
#pragma unroll
    for (int mt = 0; mt < MT; ++mt)
#pragma unroll
      for (int nt = 0; nt < 4; ++nt)
        acc[mt][nt] = mfma32(af[mt], bfr[nt], acc[mt][nt]);
  }

#pragma unroll
  for (int nt = 0; nt < 4; ++nt) {
    int col = nbase + n0w + nt * 16 + l15;
    float bc = bias[col];
#pragma unroll
    for (int mt = 0; mt < MT; ++mt)
#pragma unroll
      for (int r = 0; r < 4; ++r) {
        int row = mbase + m0w + mt * 16 + quad * 4 + r;
        float vv = acc[mt][nt][r] + bc;
        if (OUTF32)
          ((float*)Cv)[(size_t)row * DM + col] = vv;
        else
          ((bf16_t*)Cv)[(size_t)row * DM + col] = (bf16_t)vv;
      }
  }
}

__global__ __launch_bounds__(256) void gemm_qkv_kernel(
    const bf16_t* xq, const bf16_t* xk, const bf16_t* xv,
    const bf16_t* wq, const bf16_t* wk, const bf16_t* wv,
    const float* bq, const float* bk, const float* bv,
    bf16_t* cq, bf16_t* ck, bf16_t* cv) {
  const bf16_t* Xarr[3] = {xq, xk, xv};
  const bf16_t* Warr[3] = {wq, wk, wv};
  const float* barr[3] = {bq, bk, bv};
  bf16_t* Carr[3] = {cq, ck, cv};
  int z = blockIdx.z;
  gemm_core<128, false>(Xarr[z], Warr[z], barr[z], Carr[z], blockIdx.x, blockIdx.y);
}

__global__ __launch_bounds__(256) void gemm_wo_kernel(const bf16_t* X, const bf16_t* W,
                                                      const float* bias, float* C) {
  gemm_core<64, true>(X, W, bias, C, blockIdx.x, blockIdx.y);
}

// ---------------------------------------------------------------------------
// Vt[(b*8+h)*64 + d][m] = Vb[b*1024 + m][h*64 + d]
// ---------------------------------------------------------------------------
__global__ __launch_bounds__(256) void vtrans_kernel(const bf16_t* __restrict__ Vb,
                                                     bf16_t* __restrict__ Vt) {
  int mt = blockIdx.x;
  int bh = blockIdx.y;
  int b = bh >> 3, h = bh & 7;
  __shared__ bf16_t Ts[64][66];
  int t = threadIdx.x;
#pragma unroll
  for (int f = 0; f < 2; ++f) {
    int chunk = t + f * 256;
    int row = chunk >> 3;
    int c8 = (chunk & 7) * 8;
    bf16x8 v = *(const bf16x8*)&Vb[(size_t)(b * SEQ + mt * 64 + row) * DM + h * DK + c8];
#pragma unroll
    for (int j = 0; j < 8; ++j) Ts[c8 + j][row] = v[j];
  }
  __syncthreads();
#pragma unroll
  for (int f = 0; f < 2; ++f) {
    int chunk = t + f * 256;
    int d = chunk >> 3;
    int m8 = (chunk & 7) * 8;
    bf16x8 o;
#pragma unroll
    for (int j = 0; j < 8; ++j) o[j] = Ts[d][m8 + j];
    *(bf16x8*)&Vt[((size_t)(bh * DK + d)) * SEQ + mt * 64 + m8] = o;
  }
}

// ---------------------------------------------------------------------------
// Flash attention (R5 math, pipelined staging).  Per block: 64 q x (h,b).
// S^T = mfma(K,Q) -> softmax per q=l15 -> wave-private LDS P -> PV.
// K/V(mt+1) and G(mt+1) prefetched into VGPRs during compute(mt).
// ---------------------------------------------------------------------------
__global__ __launch_bounds__(256) void flash_mfma_kernel(const bf16_t* __restrict__ Qb,
                                                         const bf16_t* __restrict__ Kb,
                                                         const bf16_t* __restrict__ Vt,
                                                         const bf16_t* __restrict__ G,
                                                         bf16_t* __restrict__ Ab) {
  int qt = blockIdx.x, h = blockIdx.y, b = blockIdx.z;
  __shared__ bf16_t Qs[64][72];
  __shared__ bf16_t Ks[64][72];
  __shared__ bf16_t Vs[64][72];  // [d][kv]
  __shared__ bf16_t Ps[64][72];  // [q][kv], rows wave-private
  int t = threadIdx.x, lane = t & 63, w = t >> 6;
  int quad = lane >> 4, l15 = lane & 15;

#pragma unroll
  for (int f = 0; f < 2; ++f) {
    int chunk = t + f * 256;
    int row = chunk >> 3, k8 = (chunk & 7) * 8;
    *(bf16x8*)&Qs[row][k8] =
        *(const bf16x8*)&Qb[(size_t)(b * SEQ + qt * 64 + row) * DM + h * DK + k8];
  }
  __syncthreads();
  bf16x8 aq0 = *(const bf16x8*)&Qs[w * 16 + l15][quad * 8];
  bf16x8 aq1 = *(const bf16x8*)&Qs[w * 16 + l15][32 + quad * 8];

  float m_st = -INFINITY, l_st = 0.f;
  f32x4 o[4] = {};
  const size_t grow = (size_t)(b * SEQ + qt * 64 + w * 16 + l15) * SEQ;

  // staging-lane map + pipelined regs
  int srow[2], sk8[2];
#pragma unroll
  for (int f = 0; f < 2; ++f) {
    int chunk = t + f * 256;
    srow[f] = chunk >> 3;
    sk8[f] = (chunk & 7) * 8;
  }
  const bf16_t* Kbase = Kb + (size_t)b * SEQ * DM + h * DK;
  const bf16_t* Vbase = Vt + (size_t)(b * NH + h) * DK * SEQ;
  bf16x8 kreg[2], vreg[2];
  bf16x4 greg[4];
#pragma unroll
  for (int f = 0; f < 2; ++f) {
    kreg[f] = *(const bf16x8*)&Kbase[(size_t)srow[f] * DM + sk8[f]];
    vreg[f] = *(const bf16x8*)&Vbase[(size_t)srow[f] * SEQ + sk8[f]];
  }
#pragma unroll
  for (int ct = 0; ct < 4; ++ct)
    greg[ct] = *(const bf16x4*)&G[grow + ct * 16 + quad * 4];

  for (int mt = 0; mt < 16; ++mt) {
    __syncthreads();  // Ks/Vs free
#pragma unroll
    for (int f = 0; f < 2; ++f) {
      *(bf16x8*)&Ks[srow[f]][sk8[f]] = kreg[f];  // vmcnt wait: loads are 1 iter old
      *(bf16x8*)&Vs[srow[f]][sk8[f]] = vreg[f];
    }
    __syncthreads();  // tiles visible
    if (mt + 1 < 16) {
#pragma unroll
      for (int f = 0; f < 2; ++f) {
        kreg[f] = *(const bf16x8*)&Kbase[(size_t)((mt + 1) * 64 + srow[f]) * DM + sk8[f]];
        vreg[f] = *(const bf16x8*)&Vbase[(size_t)srow[f] * SEQ + (mt + 1) * 64 + sk8[f]];
      }
    }

    f32x4 s[4];
#pragma unroll
    for (int ct = 0; ct < 4; ++ct) {
      bf16x8 ak0 = *(const bf16x8*)&Ks[ct * 16 + l15][quad * 8];
      bf16x8 ak1 = *(const bf16x8*)&Ks[ct * 16 + l15][32 + quad * 8];
      f32x4 z = {};
      s[ct] = mfma32(ak1, aq1, mfma32(ak0, aq0, z));
    }

    float sv[4][4];
    float rm = -INFINITY;
#pragma unroll
    for (int ct = 0; ct < 4; ++ct) {
#pragma unroll
      for (int r = 0; r < 4; ++r) {
        float x = s[ct][r] * 0.125f * (float)greg[ct][r];
        sv[ct][r] = x;
        rm = fmaxf(rm, x);
      }
    }
    // greg dead -> prefetch G(mt+1) under the softmax/PV compute
    if (mt + 1 < 16) {
#pragma unroll
      for (int ct = 0; ct < 4; ++ct)
        greg[ct] = *(const bf16x4*)&G[grow + (mt + 1) * 64 + ct * 16 + quad * 4];
    }
    rm = fmaxf(rm, __shfl_xor(rm, 16, 64));
    rm = fmaxf(rm, __shfl_xor(rm, 32, 64));
    float mnew = fmaxf(m_st, rm);
    float alpha = __expf(m_st - mnew);
    m_st = mnew;

    float rs = 0.f;
#pragma unroll
    for (int ct = 0; ct < 4; ++ct) {
      bf16x4 pb;
#pragma unroll
      for (int r = 0; r < 4; ++r) {
        float p = __expf(sv[ct][r] - mnew);
        pb[r] = (bf16_t)p;
        rs += p;
      }
      *(bf16x4*)&Ps[w * 16 + l15][ct * 16 + quad * 4] = pb;
    }
    rs += __shfl_xor(rs, 16, 64);
    rs += __shfl_xor(rs, 32, 64);
    l_st = l_st * alpha + rs;

#pragma unroll
    for (int dt = 0; dt < 4; ++dt) {
      o[dt][0] *= alpha; o[dt][1] *= alpha; o[dt][2] *= alpha; o[dt][3] *= alpha;
    }
#pragma unroll
    for (int c = 0; c < 2; ++c) {
      bf16x8 bp = *(const bf16x8*)&Ps[w * 16 + l15][c * 32 + quad * 8];
#pragma unroll
      for (int dt = 0; dt < 4; ++dt) {
        bf16x8 av = *(const bf16x8*)&Vs[dt * 16 + l15][c * 32 + quad * 8];
        o[dt] = mfma32(av, bp, o[dt]);
      }
    }
  }

  float linv = 1.0f / l_st;
  size_t qrow = (size_t)(b * SEQ + qt * 64 + w * 16 + l15);
#pragma unroll
  for (int dt = 0; dt < 4; ++dt)
#pragma unroll
    for (int r = 0; r < 4; ++r)
      Ab[qrow * DM + h * DK + dt * 16 + quad * 4 + r] = (bf16_t)(o[dt][r] * linv);
}

// ---------------------------------------------------------------------------
extern "C" void kernel_launch(void* const* d_in, const int* in_sizes, int n_in,
                              void* d_out, int out_size, void* d_ws, size_t ws_size,
                              hipStream_t stream) {
  const float* query = (const float*)d_in[0];
  const float* key = (const float*)d_in[1];
  const float* value = (const float*)d_in[2];
  const float* wc = (const float*)d_in[3];
  const float* Wq = (const float*)d_in[4];
  const float* bq = (const float*)d_in[5];
  const float* Wk = (const float*)d_in[6];
  const float* bk = (const float*)d_in[7];
  const float* Wv = (const float*)d_in[8];
  const float* bv = (const float*)d_in[9];
  const float* Wo = (const float*)d_in[10];
  const float* bo = (const float*)d_in[11];
  float* out = (float*)d_out;

  const size_t ACT = (size_t)ROWS * DM;
  const size_t WSZ = (size_t)DM * DM;
  bf16_t* Qb = (bf16_t*)d_ws;
  bf16_t* Kb = Qb + ACT;
  bf16_t* Vb = Kb + ACT;
  bf16_t* Vt = Vb + ACT;
  bf16_t* Ab = Vt + ACT;
  bf16_t* G = Ab + ACT;
  bf16_t* Xq = G + (size_t)BS * SEQ * SEQ;
  bf16_t* Xk = Xq + ACT;
  bf16_t* Xv = Xk + ACT;
  bf16_t* Wqb = Xv + ACT;
  bf16_t* Wkb = Wqb + WSZ;
  bf16_t* Wvb = Wkb + WSZ;
  bf16_t* Wob = Wvb + WSZ;

  cvt_kernel<<<1664, 256, 0, stream>>>(query, key, value, Wq, Wk, Wv, Wo,
                                       Xq, Xk, Xv, Wqb, Wkb, Wvb, Wob);

  wc_softmax_kernel<<<BS * SEQ, 256, 0, stream>>>(wc, G);

  gemm_qkv_kernel<<<dim3(ROWS / 128, DM / 128, 3), 256, 0, stream>>>(
      Xq, Xk, Xv, Wqb, Wkb, Wvb, bq, bk, bv, Qb, Kb, Vb);

  vtrans_kernel<<<dim3(16, 64), 256, 0, stream>>>(Vb, Vt);

  flash_mfma_kernel<<<dim3(SEQ / 64, NH, BS), 256, 0, stream>>>(Qb, Kb, Vt, G, Ab);

  gemm_wo_kernel<<<dim3(ROWS / 64, DM / 128), 256, 0, stream>>>(Ab, Wob, bo, out);
}